// Round 12
// baseline (86.805 us; speedup 1.0000x reference)
//
#include <hip/hip_runtime.h>

#define BATCH 8
#define CIN   64
#define COUT  64
#define LEN   16384
#define KS    5
#define PADW  2
#define LP    (LEN + 2*PADW)
#define TT    64
#define WPOS  80             // staged window rows (relative p = 0..79)
#define XM    6              // S0 = t0 - 6
#define Y_OFF 0              // Y: [80][320] bf16, row = 640 B, swizzled
#define X_OFF 51200          // xt: [80][64] bf16, row = 128 B, swizzled (union w/ otile)
#define OT_OFF 51200         // otile: [64][33] f32 (8448 B), used after xt is dead

typedef __attribute__((ext_vector_type(8)))  short short8;
typedef __attribute__((ext_vector_type(4)))  float f32x4;

__device__ __forceinline__ unsigned short bf16r(float f) {
    unsigned u = __builtin_bit_cast(unsigned, f);
    u += 0x7FFF + ((u >> 16) & 1);          // RNE
    return (unsigned short)(u >> 16);
}
__device__ __forceinline__ float bq(float v) {   // round-to-bf16, back to f32
    return __builtin_bit_cast(float, (unsigned)bf16r(v) << 16);
}
__device__ __forceinline__ unsigned pack_bf16x2(float a, float b) {
    return (unsigned)bf16r(a) | ((unsigned)bf16r(b) << 16);
}
__device__ __forceinline__ int reflmap(int s) {  // padded idx -> x idx
    return (s < PADW) ? (PADW - s) : ((s < LEN + PADW) ? (s - PADW) : (2*LEN - s));
}

// W (f32 [o][c][k]) -> bf16 A-frags for mfma_f32_16x16x32_bf16.
// A rows m = k*64 + o (M=320), cols c (K=64).
// wf[((rt*2 + kc)*64 + lane)*8 + e]: row = rt*16+(lane&15), c = kc*32+(lane>>4)*8+e
__global__ void wfrag_kernel(const float* __restrict__ w, unsigned short* __restrict__ wf) {
    int el = blockIdx.x * 256 + threadIdx.x;     // 20480 total
    int e    = el & 7;
    int lane = (el >> 3) & 63;
    int tile = el >> 9;                          // 0..39
    int kc = tile & 1, rt = tile >> 1;
    int row = rt * 16 + (lane & 15);             // m = k*64 + o
    int ktap = row >> 6, o = row & 63;
    int c = kc * 32 + ((lane >> 4) << 3) + e;
    wf[el] = bf16r(w[(o * 64 + c) * 5 + ktap]);
}

__global__ __launch_bounds__(256, 2) void fused_kernel(
    const float* __restrict__ x, const float* __restrict__ offs,
    const float* __restrict__ wgt, const unsigned short* __restrict__ wf,
    const float* __restrict__ bias, float* __restrict__ out)
{
    __shared__ __align__(16) char lds[61440];

    const int tid  = threadIdx.x;
    const int bid  = blockIdx.x;
    const int bt   = (bid & 7) * 256 + (bid >> 3);   // XCD swizzle (2048 % 8 == 0)
    const int b    = bt >> 8;
    const int t0   = (bt & 255) * TT;
    const int w    = tid >> 6;
    const int lane = tid & 63;
    const int pl   = lane & 15;
    const int lh   = lane >> 4;
    const int S0   = t0 - XM;

    const float* xb0 = x + (size_t)b * CIN * LEN;

    // ---- A-frags: 10 per wave, reg-resident ----
    short8 wr[5][2];
    #pragma unroll
    for (int rti = 0; rti < 5; ++rti)
        #pragma unroll
        for (int kc = 0; kc < 2; ++kc)
            wr[rti][kc] = *(const short8*)&wf[((((w * 5 + rti) * 2) + kc) * 64 + lane) * 8];

    // ---- stage xt[p][c] bf16, swizzled: byte = X_OFF + p*128 + (2c ^ ((p&7)<<4)) ----
    if (t0 >= 8 && t0 <= LEN - 72 - 2) {             // interior: x idx = t0-8+p
        const float* src0 = xb0 + (t0 - 8);
        #pragma unroll
        for (int rep = 0; rep < 5; ++rep) {
            int idx = rep * 256 + tid;               // 0..1279
            int c = idx / 20, q = idx - c * 20;      // p = 4q..4q+3
            float4 vv = *(const float4*)(src0 + (size_t)c * LEN + 4 * q);
            #pragma unroll
            for (int i = 0; i < 4; ++i) {
                int p = 4 * q + i;
                float vi = (i == 0) ? vv.x : (i == 1) ? vv.y : (i == 2) ? vv.z : vv.w;
                *(unsigned short*)(lds + X_OFF + p * 128 + ((2 * c) ^ ((p & 7) << 4))) = bf16r(vi);
            }
        }
    } else {                                         // edge tiles (16 of 2048)
        #pragma unroll
        for (int rep = 0; rep < 20; ++rep) {
            int idx = rep * 256 + tid;               // 0..5119
            int p = idx >> 6, c = idx & 63;
            int sp = min(max(S0 + p, 0), LP - 1);
            float v = xb0[(size_t)c * LEN + reflmap(sp)];
            *(unsigned short*)(lds + X_OFF + p * 128 + ((2 * c) ^ ((p & 7) << 4))) = bf16r(v);
        }
    }
    __syncthreads();

    // ---- dense GEMM: Y[p][m] = sum_c W'[m][c] * xt[p][c] ----
    f32x4 acc[5][5] = {};
    #pragma unroll
    for (int pt = 0; pt < 5; ++pt) {
        const int p  = pt * 16 + pl;
        const int sw = (p & 7) << 4;
        short8 b0 = *(const short8*)(lds + X_OFF + p * 128 + ((lh * 16)      ^ sw));
        short8 b1 = *(const short8*)(lds + X_OFF + p * 128 + ((64 + lh * 16) ^ sw));
        #pragma unroll
        for (int rti = 0; rti < 5; ++rti) {
            acc[rti][pt] = __builtin_amdgcn_mfma_f32_16x16x32_bf16(wr[rti][0], b0, acc[rti][pt], 0, 0, 0);
            acc[rti][pt] = __builtin_amdgcn_mfma_f32_16x16x32_bf16(wr[rti][1], b1, acc[rti][pt], 0, 0, 0);
        }
    }

    // ---- Y -> LDS bf16, swizzled: byte = p*640 + ((2m) ^ ((p&7)<<4)) ----
    #pragma unroll
    for (int rti = 0; rti < 5; ++rti)
        #pragma unroll
        for (int pt = 0; pt < 5; ++pt) {
            const int p  = pt * 16 + pl;
            const int m0 = (w * 5 + rti) * 16 + lh * 4;   // C/D row = lh*4 + r
            uint2 pk;
            pk.x = pack_bf16x2(acc[rti][pt][0], acc[rti][pt][1]);
            pk.y = pack_bf16x2(acc[rti][pt][2], acc[rti][pt][3]);
            *(uint2*)(lds + p * 640 + ((2 * m0) ^ ((p & 7) << 4))) = pk;
        }
    __syncthreads();

    // ---- combine: out[o][t] = sum_k lerp(Y[r0][k*64+o], Y[r0+1][k*64+o], f) ----
    #pragma unroll 1
    for (int h = 0; h < 2; ++h) {
        #pragma unroll 1
        for (int j = 0; j < 8; ++j) {
            const int tl = h * 32 + w * 8 + j;
            const int t  = t0 + tl;
            float accv = 0.0f;
            #pragma unroll
            for (int k = 0; k < KS; ++k) {
                float off = offs[((size_t)(b * LEN + t)) * KS + k];
                float T = (float)(t + k) + off;
                T = fminf(fmaxf(T, 0.0f), (float)(LP - 1));
                int i0 = (int)floorf(T);
                i0 = min(i0, LP - 2); i0 = max(i0, 0);
                float f = T - (float)i0;
                int r0 = i0 - S0;
                if ((unsigned)r0 <= (unsigned)(WPOS - 2)) {   // wave-uniform branch
                    unsigned y0 = *(const unsigned short*)(lds + r0 * 640 + ((k * 128 + 2 * lane) ^ ((r0 & 7) << 4)));
                    int r1 = r0 + 1;
                    unsigned y1 = *(const unsigned short*)(lds + r1 * 640 + ((k * 128 + 2 * lane) ^ ((r1 & 7) << 4)));
                    float g0 = __builtin_bit_cast(float, y0 << 16);
                    float g1 = __builtin_bit_cast(float, y1 << 16);
                    accv += g0 + f * (g1 - g0);
                } else {                                       // exact fallback (rare)
                    int j0 = reflmap(i0), j1 = reflmap(i0 + 1);
                    float y0 = 0.0f, y1 = 0.0f;
                    for (int c = 0; c < CIN; ++c) {
                        float wv = bq(wgt[((lane * 64 + c)) * 5 + k]);
                        y0 = fmaf(wv, bq(xb0[(size_t)c * LEN + j0]), y0);
                        y1 = fmaf(wv, bq(xb0[(size_t)c * LEN + j1]), y1);
                    }
                    accv += y0 + f * (y1 - y0);
                }
            }
            *(float*)(lds + OT_OFF + (lane * 33 + (tl & 31)) * 4) = accv + bias[lane];
        }
        __syncthreads();
        // ---- coalesced store of this half ----
        {
            const int og = tid >> 5, tl32 = tid & 31;
            #pragma unroll
            for (int q = 0; q < 8; ++q) {
                int oo = og * 8 + q;
                float v = *(const float*)(lds + OT_OFF + (oo * 33 + tl32) * 4);
                out[((size_t)(b * COUT + oo)) * LEN + t0 + h * 32 + tl32] = v;
            }
        }
        __syncthreads();
    }
}

extern "C" void kernel_launch(void* const* d_in, const int* in_sizes, int n_in,
                              void* d_out, int out_size, void* d_ws, size_t ws_size,
                              hipStream_t stream) {
    const float* x    = (const float*)d_in[0];
    const float* offs = (const float*)d_in[1];
    const float* w    = (const float*)d_in[2];
    const float* bias = (const float*)d_in[3];
    float* out = (float*)d_out;
    unsigned short* wf = (unsigned short*)d_ws;   // 40960 B

    wfrag_kernel<<<80, 256, 0, stream>>>(w, wf);
    fused_kernel<<<BATCH * (LEN / TT), 256, 0, stream>>>(x, offs, w, wf, bias, out);
}

// Round 13
// 51.104 us; speedup vs baseline: 1.6986x; 1.6986x over previous
//
#include <hip/hip_runtime.h>

#define BATCH 8
#define CIN   64
#define COUT  64
#define LEN   16384
#define KS    5
#define PADW  2
#define LP    (LEN + 2*PADW)
#define TT    64
#define WPOS  80             // staged window rows
#define XM    6              // S0 = t0 - 6 (padded coords); x base = t0 - 8 (aligned)
#define Y_OFF 0              // Y: [80][320] bf16, row = 640 B, swizzled
#define X_OFF 51200          // xt: [80][64] bf16, row 128 B, swizzled
#define OT_OFF 51200         // otile: [64][33] f32 (8448 B), reuses xt after GEMM
#define RF_OFF 61440         // rfQ: 320 x uint2 (2560 B); rfF: 320 x f32 (1280 B)

typedef __attribute__((ext_vector_type(8)))  short short8;
typedef __attribute__((ext_vector_type(4)))  float f32x4;

__device__ __forceinline__ unsigned short bf16r(float f) {
    unsigned u = __builtin_bit_cast(unsigned, f);
    u += 0x7FFF + ((u >> 16) & 1);          // RNE
    return (unsigned short)(u >> 16);
}
__device__ __forceinline__ float bq(float v) {
    return __builtin_bit_cast(float, (unsigned)bf16r(v) << 16);
}
__device__ __forceinline__ unsigned pack_bf16x2(float a, float b) {
    return (unsigned)bf16r(a) | ((unsigned)bf16r(b) << 16);
}
__device__ __forceinline__ int reflmap(int s) {  // padded idx -> x idx
    return (s < PADW) ? (PADW - s) : ((s < LEN + PADW) ? (s - PADW) : (2*LEN - s));
}

// W (f32 [o][c][k]) -> bf16 A-frags for mfma_f32_16x16x32_bf16.
// A rows m = k*64 + o (M=320), cols c (K=64).
__global__ void wfrag_kernel(const float* __restrict__ w, unsigned short* __restrict__ wf) {
    int el = blockIdx.x * 256 + threadIdx.x;     // 20480 total
    int e    = el & 7;
    int lane = (el >> 3) & 63;
    int tile = el >> 9;                          // 0..39
    int kc = tile & 1, rt = tile >> 1;
    int row = rt * 16 + (lane & 15);             // m = k*64 + o
    int ktap = row >> 6, o = row & 63;
    int c = kc * 32 + ((lane >> 4) << 3) + e;
    wf[el] = bf16r(w[(o * 64 + c) * 5 + ktap]);
}

__global__ __launch_bounds__(256, 2) void fused_kernel(
    const float* __restrict__ x, const float* __restrict__ offs,
    const float* __restrict__ wgt, const unsigned short* __restrict__ wf,
    const float* __restrict__ bias, float* __restrict__ out)
{
    __shared__ __align__(16) char lds[65280];

    const int tid  = threadIdx.x;
    const int bid  = blockIdx.x;
    const int bt   = (bid & 7) * 256 + (bid >> 3);   // XCD swizzle (2048 % 8 == 0)
    const int b    = bt >> 8;
    const int t0   = (bt & 255) * TT;
    const int w    = tid >> 6;
    const int lane = tid & 63;
    const int pl   = lane & 15;
    const int lh   = lane >> 4;
    const int S0   = t0 - XM;
    const unsigned ln2 = (unsigned)(2 * lane);

    const float* xb0 = x + (size_t)b * CIN * LEN;
    const float biasv = bias[lane];

    // ---- A-frags: 10 per wave, reg-resident ----
    short8 wr[5][2];
    #pragma unroll
    for (int rti = 0; rti < 5; ++rti)
        #pragma unroll
        for (int kc = 0; kc < 2; ++kc)
            wr[rti][kc] = *(const short8*)&wf[((((w * 5 + rti) * 2) + kc) * 64 + lane) * 8];

    // ---- stage xt[p][c] bf16, swizzled ----
    if (t0 >= 8 && t0 <= LEN - 72) {
        const float* src0 = xb0 + (t0 - 8);
        #pragma unroll
        for (int rep = 0; rep < 5; ++rep) {
            int idx = rep * 256 + tid;               // 0..1279
            int c = idx / 20, q = idx - c * 20;
            float4 vv = *(const float4*)(src0 + (size_t)c * LEN + 4 * q);
            #pragma unroll
            for (int i = 0; i < 4; ++i) {
                int p = 4 * q + i;
                float vi = (i == 0) ? vv.x : (i == 1) ? vv.y : (i == 2) ? vv.z : vv.w;
                *(unsigned short*)(lds + X_OFF + p * 128 + ((2 * c) ^ ((p & 7) << 4))) = bf16r(vi);
            }
        }
    } else {
        #pragma unroll
        for (int rep = 0; rep < 20; ++rep) {
            int idx = rep * 256 + tid;               // 0..5119
            int p = idx >> 6, c = idx & 63;
            int sp = min(max(S0 + p, 0), LP - 1);
            float v = xb0[(size_t)c * LEN + reflmap(sp)];
            *(unsigned short*)(lds + X_OFF + p * 128 + ((2 * c) ^ ((p & 7) << 4))) = bf16r(v);
        }
    }

    // ---- rf precompute: 320 tasks, offs fully linear in task ----
    {
        const size_t obase = ((size_t)b * LEN + t0) * KS;
        #pragma unroll
        for (int rep = 0; rep < 2; ++rep) {
            int task = rep * 256 + tid;
            if (task < 320) {
                int tloc = task / 5, k = task - 5 * tloc;
                float off = offs[obase + task];
                float T = (float)(t0 + tloc + k) + off;
                T = fminf(fmaxf(T, 0.0f), (float)(LP - 1));
                int i0 = (int)floorf(T);
                i0 = min(i0, LP - 2); i0 = max(i0, 0);
                float f = T - (float)i0;
                int r0 = i0 - S0;
                unsigned bad = ((unsigned)r0 > (unsigned)(WPOS - 2)) ? 0x80000000u : 0u;
                int r0c = min(max(r0, 0), WPOS - 2);
                unsigned Q0 = (unsigned)(r0c * 640 + k * 128) | ((unsigned)(r0c & 7) << 4) | bad;
                int r1 = r0c + 1;
                unsigned Q1 = (unsigned)(r1 * 640 + k * 128) | ((unsigned)(r1 & 7) << 4);
                *(uint2*)(lds + RF_OFF + task * 8) = uint2{Q0, Q1};
                *(float*)(lds + RF_OFF + 2560 + task * 4) = f;
            }
        }
    }
    __syncthreads();

    // ---- dense GEMM: Y[p][m] = sum_c W'[m][c] * xt[p][c] ----
    f32x4 acc[5][5] = {};
    #pragma unroll
    for (int pt = 0; pt < 5; ++pt) {
        const int p  = pt * 16 + pl;
        const int sw = (p & 7) << 4;
        short8 b0 = *(const short8*)(lds + X_OFF + p * 128 + ((lh * 16)      ^ sw));
        short8 b1 = *(const short8*)(lds + X_OFF + p * 128 + ((64 + lh * 16) ^ sw));
        #pragma unroll
        for (int rti = 0; rti < 5; ++rti) {
            acc[rti][pt] = __builtin_amdgcn_mfma_f32_16x16x32_bf16(wr[rti][0], b0, acc[rti][pt], 0, 0, 0);
            acc[rti][pt] = __builtin_amdgcn_mfma_f32_16x16x32_bf16(wr[rti][1], b1, acc[rti][pt], 0, 0, 0);
        }
    }
    __syncthreads();                                  // xt dead; otile region free

    // ---- Y -> LDS bf16, swizzled ----
    #pragma unroll
    for (int rti = 0; rti < 5; ++rti)
        #pragma unroll
        for (int pt = 0; pt < 5; ++pt) {
            const int p  = pt * 16 + pl;
            const int m0 = (w * 5 + rti) * 16 + lh * 4;
            uint2 pk;
            pk.x = pack_bf16x2(acc[rti][pt][0], acc[rti][pt][1]);
            pk.y = pack_bf16x2(acc[rti][pt][2], acc[rti][pt][3]);
            *(uint2*)(lds + p * 640 + ((2 * m0) ^ ((p & 7) << 4))) = pk;
        }
    __syncthreads();

    // ---- combine, 2 halves of 32 t ----
    #pragma unroll 1
    for (int h = 0; h < 2; ++h) {
        #pragma unroll
        for (int j = 0; j < 8; ++j) {
            const int tl = h * 32 + w * 8 + j;
            float accv = biasv;
            int bad = 0;
            #pragma unroll
            for (int k = 0; k < KS; ++k) {
                const int tk = tl * 5 + k;
                uint2 q  = *(const uint2*)(lds + RF_OFF + tk * 8);
                float f  = *(const float*)(lds + RF_OFF + 2560 + tk * 4);
                bad |= (int)q.x;
                unsigned a0 = (q.x ^ ln2) & 0xFFFFu;
                unsigned a1 = (q.y ^ ln2) & 0xFFFFu;
                unsigned y0 = *(const unsigned short*)(lds + a0);
                unsigned y1 = *(const unsigned short*)(lds + a1);
                float g0 = __builtin_bit_cast(float, y0 << 16);
                float g1 = __builtin_bit_cast(float, y1 << 16);
                accv += fmaf(f, g1 - g0, g0);
            }
            if (__builtin_expect(bad < 0, 0)) {       // wave-uniform, ~never
                const int t = t0 + tl;
                accv = biasv;
                for (int k = 0; k < KS; ++k) {
                    float off = offs[((size_t)(b * LEN + t)) * KS + k];
                    float T = (float)(t + k) + off;
                    T = fminf(fmaxf(T, 0.0f), (float)(LP - 1));
                    int i0 = (int)floorf(T);
                    i0 = min(i0, LP - 2); i0 = max(i0, 0);
                    float f = T - (float)i0;
                    int j0 = reflmap(i0), j1 = reflmap(i0 + 1);
                    float y0 = 0.0f, y1 = 0.0f;
                    for (int c = 0; c < CIN; ++c) {
                        float wv = bq(wgt[(lane * 64 + c) * 5 + k]);
                        y0 = fmaf(wv, bq(xb0[(size_t)c * LEN + j0]), y0);
                        y1 = fmaf(wv, bq(xb0[(size_t)c * LEN + j1]), y1);
                    }
                    accv += y0 + f * (y1 - y0);
                }
            }
            *(float*)(lds + OT_OFF + (lane * 33 + (tl & 31)) * 4) = accv;
        }
        __syncthreads();
        {
            const int og = tid >> 5, t32 = tid & 31;
            #pragma unroll
            for (int qq = 0; qq < 8; ++qq) {
                int oo = og * 8 + qq;
                float v = *(const float*)(lds + OT_OFF + (oo * 33 + t32) * 4);
                out[((size_t)(b * COUT + oo)) * LEN + t0 + h * 32 + t32] = v;
            }
        }
        __syncthreads();
    }
}

extern "C" void kernel_launch(void* const* d_in, const int* in_sizes, int n_in,
                              void* d_out, int out_size, void* d_ws, size_t ws_size,
                              hipStream_t stream) {
    const float* x    = (const float*)d_in[0];
    const float* offs = (const float*)d_in[1];
    const float* w    = (const float*)d_in[2];
    const float* bias = (const float*)d_in[3];
    float* out = (float*)d_out;
    unsigned short* wf = (unsigned short*)d_ws;   // 40960 B

    wfrag_kernel<<<80, 256, 0, stream>>>(w, wf);
    fused_kernel<<<BATCH * (LEN / TT), 256, 0, stream>>>(x, offs, w, wf, bias, out);
}

// Round 14
// 38.151 us; speedup vs baseline: 2.2753x; 1.3395x over previous
//
#include <hip/hip_runtime.h>

#define BATCH 8
#define CIN   64
#define COUT  64
#define LEN   16384
#define KS    5
#define PADW  2
#define LP    (LEN + 2*PADW)
#define TTB   128            // cols per block (2 subtiles of 64)
#define XROWS 104            // staged rows per subtile window
#define XM    14             // window start S0 = t0s - XM (padded coords)

typedef __attribute__((ext_vector_type(8)))  short short8;
typedef __attribute__((ext_vector_type(4)))  float f32x4;
typedef __attribute__((ext_vector_type(8)))  unsigned short ushort8;

__device__ __forceinline__ unsigned short bf16r(float f) {
    unsigned u = __builtin_bit_cast(unsigned, f);
    u += 0x7FFF + ((u >> 16) & 1);          // RNE
    return (unsigned short)(u >> 16);
}
__device__ __forceinline__ int reflmap(int s) {  // padded idx -> x idx
    return (s < PADW) ? (PADW - s) : ((s < LEN + PADW) ? (s - PADW) : (2*LEN - s));
}

// W (f32 [o][c][k]) -> bf16 A-frags for mfma_f32_16x16x32_bf16, K k-major
// (ck' = ktap*64 + c).  wf[((ot*10 + kk)*64 + lane)*8 + e]
__global__ void wfrag_kernel(const float* __restrict__ w, unsigned short* __restrict__ wf) {
    int el = blockIdx.x * 256 + threadIdx.x;          // 20480 total
    int e    = el & 7;
    int lane = (el >> 3) & 63;
    int kk   = (el >> 9) % 10;
    int ot   = el / 5120;
    int o    = ot * 16 + (lane & 15);
    int kg   = kk * 32 + ((lane >> 4) << 3) + e;      // ck' 0..319
    int ktap = kg >> 6;
    int c    = kg & 63;
    wf[el] = bf16r(w[(o * 64 + c) * 5 + ktap]);
}

__global__ __launch_bounds__(256, 4) void deform_mfma_kernel(
    const float* __restrict__ x, const float* __restrict__ offs,
    const unsigned short* __restrict__ wf, const float* __restrict__ bias,
    float* __restrict__ out)
{
    __shared__ __align__(16) unsigned short xtl[2][XROWS * 64];   // 2 x 13312 B

    const int tid = threadIdx.x;
    const int bid = blockIdx.x;
    const int bt  = (bid & 7) * 128 + (bid >> 3);    // XCD swizzle (1024 = 8*128)
    const int b   = bt >> 7;
    const int T0  = (bt & 127) * TTB;
    const int w   = tid >> 6;
    const int lane = tid & 63;
    const int pl  = lane & 15;
    const int s   = lane >> 4;

    const float* xb0 = x + (size_t)b * CIN * LEN;
    const unsigned short* wfl = wf + (size_t)lane * 8;

    // ---- preload offsets for both subtiles (removes global lat from loop) ----
    float of[2][KS];
    #pragma unroll
    for (int it = 0; it < 2; ++it) {
        const int tc = T0 + it * 64 + w * 16 + pl;
        #pragma unroll
        for (int k = 0; k < KS; ++k)
            of[it][k] = offs[((size_t)(b * LEN + tc)) * KS + k];
    }

    float4 sA[4], sB[4];
    int stg_fast;

    // row r of a subtile window = xp[S0+r]; fast path x base = t0s-16 (16B aligned)
#define STAGE_LOAD(t0s)                                                        \
    stg_fast = ((t0s) >= 16 && (t0s) + 88 <= LEN);                             \
    if (stg_fast) {                                                            \
        const float* src0 = xb0 + ((t0s) - 16);                                \
        _Pragma("unroll")                                                      \
        for (int rep = 0; rep < 4; ++rep) {                                    \
            int task = rep * 256 + tid;          /* 832 = 64 ch x 13 strips */ \
            if (task < 832) {                                                  \
                int c = task / 13, q = task - c * 13;                          \
                const float* p = src0 + (size_t)c * LEN + 8 * q;               \
                sA[rep] = *(const float4*)p;                                   \
                sB[rep] = *(const float4*)(p + 4);                             \
            }                                                                  \
        }                                                                      \
    }

#define STAGE_WRITE(dst, t0s)                                                  \
    if (stg_fast) {                                                            \
        _Pragma("unroll")                                                      \
        for (int rep = 0; rep < 4; ++rep) {                                    \
            int task = rep * 256 + tid;                                        \
            if (task < 832) {                                                  \
                int c = task / 13, q = task - c * 13;                          \
                float vv[8] = {sA[rep].x, sA[rep].y, sA[rep].z, sA[rep].w,     \
                               sB[rep].x, sB[rep].y, sB[rep].z, sB[rep].w};    \
                _Pragma("unroll")                                              \
                for (int i = 0; i < 8; ++i) {                                  \
                    int r = 8 * q + i;                                         \
                    *(unsigned short*)((char*)(dst) + r * 128 +                \
                        ((2 * c) ^ ((r & 7) << 4))) = bf16r(vv[i]);            \
                }                                                              \
            }                                                                  \
        }                                                                      \
    } else {                                                                   \
        const int S0e = (t0s) - XM;                                            \
        _Pragma("unroll")                                                      \
        for (int rep = 0; rep < 26; ++rep) {                                   \
            int idx = rep * 256 + tid;           /* 6656 = 104 x 64 */         \
            int r = idx >> 6, c = idx & 63;                                    \
            int sp = min(max(S0e + r, 0), LP - 1);                             \
            *(unsigned short*)((char*)(dst) + r * 128 +                        \
                ((2 * c) ^ ((r & 7) << 4))) = bf16r(xb0[(size_t)c * LEN + reflmap(sp)]); \
        }                                                                      \
    }

#define LERPP(pk, j, w0, w1, f)                                                \
    {                                                                          \
        float g0a = __builtin_bit_cast(float, (w0) << 16);                     \
        float g1a = __builtin_bit_cast(float, (w1) << 16);                     \
        float g0b = __builtin_bit_cast(float, (w0) & 0xFFFF0000u);             \
        float g1b = __builtin_bit_cast(float, (w1) & 0xFFFF0000u);             \
        pk[2*(j)]   = bf16r(fmaf(f, g1a - g0a, g0a));                          \
        pk[2*(j)+1] = bf16r(fmaf(f, g1b - g0b, g0b));                          \
    }

#define GST(kk, CHECKED)                                                       \
    {                                                                          \
        const int k = (kk) >> 1;                                               \
        const int m = (((kk) & 1) << 2) + s;         /* chunk 0..7 */          \
        const float f = frr[k];                                                \
        ushort8 pk;                                                            \
        if (!(CHECKED) || (unsigned)r0r[k] <= (unsigned)(XROWS - 2)) {         \
            const int r0 = r0r[k], r1 = r0r[k] + 1;                            \
            uint4 u0 = *(const uint4*)((const char*)xbuf + r0 * 128 + ((m * 16) ^ ((r0 & 7) << 4))); \
            uint4 u1 = *(const uint4*)((const char*)xbuf + r1 * 128 + ((m * 16) ^ ((r1 & 7) << 4))); \
            LERPP(pk, 0, u0.x, u1.x, f) LERPP(pk, 1, u0.y, u1.y, f)            \
            LERPP(pk, 2, u0.z, u1.z, f) LERPP(pk, 3, u0.w, u1.w, f)            \
        } else {                                                               \
            int j0 = reflmap(i0r[k]), j1 = reflmap(i0r[k] + 1);                \
            const float* xc = xb0 + (size_t)(m << 3) * LEN;                    \
            _Pragma("unroll")                                                  \
            for (int e = 0; e < 8; ++e) {                                      \
                float g0 = xc[j0], g1 = xc[j1];                                \
                pk[e] = bf16r(fmaf(f, g1 - g0, g0));                           \
                xc += LEN;                                                     \
            }                                                                  \
        }                                                                      \
        short8 bv = __builtin_bit_cast(short8, pk);                            \
        short8 a0 = *(const short8*)&wfl[(0 * 10 + (kk)) * 512];               \
        short8 a1 = *(const short8*)&wfl[(1 * 10 + (kk)) * 512];               \
        short8 a2 = *(const short8*)&wfl[(2 * 10 + (kk)) * 512];               \
        short8 a3 = *(const short8*)&wfl[(3 * 10 + (kk)) * 512];               \
        acc0 = __builtin_amdgcn_mfma_f32_16x16x32_bf16(a0, bv, acc0, 0, 0, 0); \
        acc1 = __builtin_amdgcn_mfma_f32_16x16x32_bf16(a1, bv, acc1, 0, 0, 0); \
        acc2 = __builtin_amdgcn_mfma_f32_16x16x32_bf16(a2, bv, acc2, 0, 0, 0); \
        acc3 = __builtin_amdgcn_mfma_f32_16x16x32_bf16(a3, bv, acc3, 0, 0, 0); \
    }

#define SUBTILE(it)                                                            \
    {                                                                          \
        const int t0s = T0 + (it) * 64;                                        \
        if ((it) == 0) { STAGE_LOAD(t0s + 64); }   /* issue next-tile loads */ \
        const int S0 = t0s - XM;                                               \
        const int tc = t0s + w * 16 + pl;                                      \
        int i0r[KS]; float frr[KS]; int r0r[KS]; bool fastg = true;            \
        _Pragma("unroll")                                                      \
        for (int k = 0; k < KS; ++k) {                                         \
            float T = (float)(tc + k) + of[it][k];                             \
            T = fminf(fmaxf(T, 0.0f), (float)(LP - 1));                        \
            int i0 = (int)floorf(T);                                           \
            i0 = min(i0, LP - 2); i0 = max(i0, 0);                             \
            i0r[k] = i0; frr[k] = T - (float)i0; r0r[k] = i0 - S0;             \
            fastg = fastg && ((unsigned)(i0 - S0) <= (unsigned)(XROWS - 2));   \
        }                                                                      \
        const unsigned short* xbuf = xtl[(it)];                                \
        f32x4 acc0 = {}, acc1 = {}, acc2 = {}, acc3 = {};                      \
        if (fastg) { GST(0,0) GST(1,0) GST(2,0) GST(3,0) GST(4,0)              \
                     GST(5,0) GST(6,0) GST(7,0) GST(8,0) GST(9,0) }            \
        else       { GST(0,1) GST(1,1) GST(2,1) GST(3,1) GST(4,1)              \
                     GST(5,1) GST(6,1) GST(7,1) GST(8,1) GST(9,1) }            \
        _Pragma("unroll")                                                      \
        for (int ot = 0; ot < 4; ++ot) {                                       \
            const f32x4 a = (ot==0)?acc0:(ot==1)?acc1:(ot==2)?acc2:acc3;       \
            _Pragma("unroll")                                                  \
            for (int r = 0; r < 4; ++r) {                                      \
                int o = ot * 16 + s * 4 + r;                                   \
                out[((size_t)(b * COUT + o)) * LEN + tc] = a[r] + bias[o];     \
            }                                                                  \
        }                                                                      \
        if ((it) == 0) { STAGE_WRITE(xtl[1], t0s + 64); __syncthreads(); }     \
    }

    // ---- prologue: stage subtile 0 ----
    STAGE_LOAD(T0);
    STAGE_WRITE(xtl[0], T0);
    __syncthreads();

    SUBTILE(0)
    SUBTILE(1)

#undef SUBTILE
#undef GST
#undef LERPP
#undef STAGE_WRITE
#undef STAGE_LOAD
}

extern "C" void kernel_launch(void* const* d_in, const int* in_sizes, int n_in,
                              void* d_out, int out_size, void* d_ws, size_t ws_size,
                              hipStream_t stream) {
    const float* x    = (const float*)d_in[0];
    const float* offs = (const float*)d_in[1];
    const float* w    = (const float*)d_in[2];
    const float* bias = (const float*)d_in[3];
    float* out = (float*)d_out;
    unsigned short* wf = (unsigned short*)d_ws;   // 40960 B

    wfrag_kernel<<<80, 256, 0, stream>>>(w, wf);
    deform_mfma_kernel<<<BATCH * (LEN / TTB), 256, 0, stream>>>(x, offs, wf, bias, out);
}